// Round 8
// baseline (68.190 us; speedup 1.0000x reference)
//
#include <hip/hip_runtime.h>
#include <math.h>

// ParametricEQ: 5-section cascaded biquad over (32, 131072).
// Single 10-state linear recurrence z' = A z + b x (A block-lower-triangular).
//   K1 setup: RBJ coeffs (fp64) + P_m = A^(16*2^m) m=0..12; zero publish flags.
//   K2 main (1024 blocks x 256 thr; thread = 16-sample chunk, block = 4096):
//     x->regs; zero-state cascade -> chunk state; in-wave KS (P_0..P_5, LDS,
//     triangular matvec); block agg via P_6; publish (release store, agent);
//     wave0: acquire-spin on 32 sibling flags; KS over 32 block aggs
//     (P_8..P_12); per-thread reconstruction (triangular matvecs);
//     final cascade -> y.

#define NB 32
#define LCH 16
#define T_LEN 131072
#define CPB 256                 // chunks per block
#define SPB 32                  // blocks per batch
#define NPOW 13
#define PROW 12                 // padded row stride (floats) in LDS
#define PMAT (10 * PROW)

__constant__ double c_lo[15] = {-12.0,   20.0, 0.1,
                                -12.0,   20.0, 0.1,
                                -12.0,  200.0, 0.1,
                                -12.0, 2000.0, 0.1,
                                -12.0, 4000.0, 0.1};
__constant__ double c_hi[15] = { 12.0,  2000.0, 10.0,
                                 12.0,   200.0, 10.0,
                                 12.0,  2000.0, 10.0,
                                 12.0, 12000.0, 10.0,
                                 12.0, 16000.0, 10.0};

// ---------------- K1: coeffs + cascade matrix powers + flag clear -----------
__global__ __launch_bounds__(128)
void eq_setup(const float* __restrict__ cp, float* __restrict__ sos_out,
              float* __restrict__ powers, unsigned int* __restrict__ flags)
{
    int b = blockIdx.x;
    int t = threadIdx.x;
    __shared__ float  sc[5][5];
    __shared__ double Abuf[2][10][10];

    if (t < SPB) flags[b * SPB + t] = 0u;   // clear publish flags (pre-main)

    if (t < 5) {
        int k = t;
        double p[3];
#pragma unroll
        for (int j = 0; j < 3; ++j) {
            int i = k * 3 + j;
            double pv = (double)cp[b * 15 + i];
            p[j] = c_lo[i] + pv * (c_hi[i] - c_lo[i]);
        }
        double A     = exp(p[0] * (M_LN10 / 40.0));
        double w0    = 2.0 * M_PI * p[1] / 44100.0;
        double alpha = sin(w0) / (2.0 * p[2]);
        double cw    = cos(w0);
        double sA    = sqrt(A);
        double b0, b1, b2, a0, a1, a2;
        if (k == 0) {            // low shelf
            b0 =     A * ((A + 1) - (A - 1) * cw + 2 * sA * alpha);
            b1 = 2 * A * ((A - 1) - (A + 1) * cw);
            b2 =     A * ((A + 1) - (A - 1) * cw - 2 * sA * alpha);
            a0 =          (A + 1) + (A - 1) * cw + 2 * sA * alpha;
            a1 =    -2 * ((A - 1) + (A + 1) * cw);
            a2 =          (A + 1) + (A - 1) * cw - 2 * sA * alpha;
        } else if (k == 4) {     // high shelf
            b0 =     A * ((A + 1) + (A - 1) * cw + 2 * sA * alpha);
            b1 = -2 * A * ((A - 1) + (A + 1) * cw);
            b2 =     A * ((A + 1) + (A - 1) * cw - 2 * sA * alpha);
            a0 =          (A + 1) - (A - 1) * cw + 2 * sA * alpha;
            a1 =     2 * ((A - 1) - (A + 1) * cw);
            a2 =          (A + 1) - (A - 1) * cw - 2 * sA * alpha;
        } else {                 // peaking
            b0 = 1.0 + alpha * A;
            b1 = -2.0 * cw;
            b2 = 1.0 - alpha * A;
            a0 = 1.0 + alpha / A;
            a1 = -2.0 * cw;
            a2 = 1.0 - alpha / A;
        }
        double inv = 1.0 / a0;
        float fb0 = (float)(b0 * inv), fb1 = (float)(b1 * inv), fb2 = (float)(b2 * inv);
        float fa1 = (float)(a1 * inv), fa2 = (float)(a2 * inv);
        float* o = sos_out + (size_t)(b * 5 + k) * 6;
        o[0] = fb0; o[1] = fb1; o[2] = fb2; o[3] = 1.0f; o[4] = fa1; o[5] = fa2;
        sc[k][0] = fb0; sc[k][1] = fb1; sc[k][2] = fb2; sc[k][3] = fa1; sc[k][4] = fa2;
    }
    __syncthreads();

    // A (10x10): column i = one-sample cascade update of basis e_i with x=0.
    // Block-LOWER-triangular (section k only feeds sections >= k); structural
    // zeros are exact and survive squaring exactly.
    if (t < 10) {
        double z[10];
#pragma unroll
        for (int i = 0; i < 10; ++i) z[i] = 0.0;
        z[t] = 1.0;
        double s = 0.0;
        double zn[10];
#pragma unroll
        for (int k = 0; k < 5; ++k) {
            double b0 = sc[k][0], b1 = sc[k][1], b2 = sc[k][2];
            double a1 = sc[k][3], a2 = sc[k][4];
            double y = b0 * s + z[2 * k];
            zn[2 * k]     = b1 * s - a1 * y + z[2 * k + 1];
            zn[2 * k + 1] = b2 * s - a2 * y;
            s = y;
        }
#pragma unroll
        for (int r = 0; r < 10; ++r) Abuf[0][r][t] = zn[r];
    }
    __syncthreads();

    int r = t / 10, cc = t % 10;
    int cur = 0;
    for (int sq = 0; sq < 16; ++sq) {
        double acc = 0.0;
        if (t < 100) {
#pragma unroll
            for (int j = 0; j < 10; ++j) acc += Abuf[cur][r][j] * Abuf[cur][j][cc];
        }
        __syncthreads();
        if (t < 100) Abuf[cur ^ 1][r][cc] = acc;
        __syncthreads();
        cur ^= 1;
        if (sq >= 3 && t < 100) {
            int m = sq - 3;   // sq=3 -> A^16 = P_0 ... sq=15 -> A^65536 = P_12
            powers[((size_t)b * NPOW + m) * 100 + t] = (float)Abuf[cur][r][cc];
        }
    }
}

// ---- triangular affine: v = P*u (+v if ACC); P block-lower-triangular,
// row rr uses cols 0..(rr|1). LDS rows padded to PROW. ----
template<bool ACC>
__device__ __forceinline__ void affineT(const float* __restrict__ P,
                                        const float u[10], float v[10])
{
#pragma unroll
    for (int rr = 0; rr < 10; ++rr) {
        const float* rp = P + rr * PROW;
        float a = ACC ? v[rr] : 0.0f;
#pragma unroll
        for (int c = 0; c <= (rr | 1); ++c) a = fmaf(rp[c], u[c], a);
        v[rr] = a;
    }
}

__device__ __forceinline__ void matvecT(const float* __restrict__ P, float v[10])
{
    float u[10];
#pragma unroll
    for (int i = 0; i < 10; ++i) u[i] = v[i];
    affineT<false>(P, u, v);
}

// ---------------- K2: main ----------------
__global__ __launch_bounds__(256, 4)
void eq_main(const float* __restrict__ x, const float* __restrict__ sos,
             const float* __restrict__ powers, float* __restrict__ agg,
             unsigned int* __restrict__ flags, float* __restrict__ y)
{
    int blk = blockIdx.x;
    int b = blk >> 5, sp = blk & (SPB - 1);
    int tid = threadIdx.x;
    int w = tid >> 6, lw = tid & 63;

    __shared__ float Pl[NPOW * PMAT];    // 13 matrices, padded rows (6.24 KB)
    __shared__ float wt[4][10];
    __shared__ float Sseed[10];

    // ---- stage P matrices into LDS ----
    {
        const float* src = powers + (size_t)b * NPOW * 100;
        for (int i = tid; i < NPOW * PMAT; i += 256) {
            int c = i % PROW;
            int r = (i / PROW) % 10;
            int m = i / PMAT;
            Pl[i] = (c < 10) ? src[m * 100 + r * 10 + c] : 0.0f;
        }
    }

    const float* s5 = sos + (size_t)(b * 5) * 6;
    float cb0[5], cb1[5], cb2[5], ca1[5], ca2[5];
#pragma unroll
    for (int k = 0; k < 5; ++k) {
        cb0[k] = s5[k * 6 + 0]; cb1[k] = s5[k * 6 + 1]; cb2[k] = s5[k * 6 + 2];
        ca1[k] = s5[k * 6 + 4]; ca2[k] = s5[k * 6 + 5];
    }

    // ---- load 16 samples to registers ----
    int c = sp * CPB + tid;                       // chunk index in batch
    const float* xp = x + (size_t)b * T_LEN + (size_t)c * LCH;
    float xr[LCH];
#pragma unroll
    for (int t0 = 0; t0 < LCH; t0 += 4) {
        float4 xv = *reinterpret_cast<const float4*>(xp + t0);
        xr[t0] = xv.x; xr[t0 + 1] = xv.y; xr[t0 + 2] = xv.z; xr[t0 + 3] = xv.w;
    }

    // ---- zero-state cascade -> chunk end state ----
    float z1[5] = {0, 0, 0, 0, 0}, z2[5] = {0, 0, 0, 0, 0};
#pragma unroll
    for (int j = 0; j < LCH; ++j) {
        float s = xr[j];
#pragma unroll
        for (int k = 0; k < 5; ++k) {
            float yk = fmaf(cb0[k], s, z1[k]);
            float u  = fmaf(cb1[k], s, z2[k]);
            z1[k] = fmaf(-ca1[k], yk, u);
            z2[k] = fmaf(-ca2[k], yk, cb2[k] * s);
            s = yk;
        }
    }
    float sv[10];
#pragma unroll
    for (int k = 0; k < 5; ++k) { sv[2 * k] = z1[k]; sv[2 * k + 1] = z2[k]; }

    __syncthreads();   // Pl staged

    // ---- in-wave KS scan over 64 chunks (P_0..P_5) ----
#pragma unroll
    for (int j = 0; j < 6; ++j) {
        const float* P = Pl + j * PMAT;
        float u[10];
#pragma unroll
        for (int i = 0; i < 10; ++i) u[i] = __shfl_up(sv[i], 1 << j);
        if (lw >= (1 << j)) affineT<true>(P, u, sv);
    }
    // exclusive in-wave prefix
    float es[10];
#pragma unroll
    for (int i = 0; i < 10; ++i) es[i] = __shfl_up(sv[i], 1);
    if (lw == 0) {
#pragma unroll
        for (int i = 0; i < 10; ++i) es[i] = 0.0f;
    }
    if (lw == 63) {
#pragma unroll
        for (int i = 0; i < 10; ++i) wt[w][i] = sv[i];
    }
    __syncthreads();

    // ---- block aggregate (thread 0): E = P6*E + wt[j], publish ----
    if (tid == 0) {
        float E[10];
#pragma unroll
        for (int i = 0; i < 10; ++i) E[i] = wt[0][i];
#pragma unroll
        for (int j = 1; j < 4; ++j) {
            matvecT(Pl + 6 * PMAT, E);
#pragma unroll
            for (int i = 0; i < 10; ++i) E[i] += wt[j][i];
        }
        float* ap = agg + (size_t)(b * SPB + sp) * 10;
#pragma unroll
        for (int i = 0; i < 10; ++i)
            __hip_atomic_store(&ap[i], E[i], __ATOMIC_RELAXED, __HIP_MEMORY_SCOPE_AGENT);
        __hip_atomic_store(&flags[b * SPB + sp], 1u, __ATOMIC_RELEASE,
                           __HIP_MEMORY_SCOPE_AGENT);
    }

    // ---- wave 0: acquire-spin on 32 sibling flags, KS over 32 aggs ----
    if (w == 0) {
        float tv[10];
#pragma unroll
        for (int i = 0; i < 10; ++i) tv[i] = 0.0f;
        if (lw < SPB) {
            while (__hip_atomic_load(&flags[b * SPB + lw], __ATOMIC_ACQUIRE,
                                     __HIP_MEMORY_SCOPE_AGENT) == 0u) {
                __builtin_amdgcn_s_sleep(2);
            }
            const float* ap = agg + (size_t)(b * SPB + lw) * 10;
#pragma unroll
            for (int i = 0; i < 10; ++i)
                tv[i] = __hip_atomic_load(&ap[i], __ATOMIC_RELAXED,
                                          __HIP_MEMORY_SCOPE_AGENT);
        }
#pragma unroll
        for (int j = 0; j < 5; ++j) {
            const float* P = Pl + (8 + j) * PMAT;
            float u[10];
#pragma unroll
            for (int i = 0; i < 10; ++i) u[i] = __shfl_up(tv[i], 1 << j);
            if (lw >= (1 << j) && lw < SPB) affineT<true>(P, u, tv);
        }
        float sd[10];
#pragma unroll
        for (int i = 0; i < 10; ++i) sd[i] = __shfl(tv[i], (sp - 1) & 63);
        if (sp == 0) {
#pragma unroll
            for (int i = 0; i < 10; ++i) sd[i] = 0.0f;
        }
        if (lw == 0) {
#pragma unroll
            for (int i = 0; i < 10; ++i) Sseed[i] = sd[i];
        }
    }
    __syncthreads();

    // ---- exact entering state: A^(16*lw) * (A^(1024*w)*S + E_w) + es ----
    float F[10];
#pragma unroll
    for (int i = 0; i < 10; ++i) F[i] = Sseed[i];
    if (w & 1) matvecT(Pl + 6 * PMAT, F);   // A^1024
    if (w & 2) matvecT(Pl + 7 * PMAT, F);   // A^2048
    {
        float Ew[10];
#pragma unroll
        for (int i = 0; i < 10; ++i) Ew[i] = 0.0f;
        for (int j = 0; j < w; ++j) {
            matvecT(Pl + 6 * PMAT, Ew);
#pragma unroll
            for (int i = 0; i < 10; ++i) Ew[i] += wt[j][i];
        }
#pragma unroll
        for (int i = 0; i < 10; ++i) F[i] += Ew[i];
    }
#pragma unroll
    for (int m = 0; m < 6; ++m) {
        if ((lw >> m) & 1) matvecT(Pl + m * PMAT, F);
    }
#pragma unroll
    for (int k = 0; k < 5; ++k) {
        z1[k] = F[2 * k]     + es[2 * k];
        z2[k] = F[2 * k + 1] + es[2 * k + 1];
    }

    // ---- final cascade from exact state -> y ----
    float* yp = y + (size_t)b * T_LEN + (size_t)c * LCH;
#pragma unroll
    for (int t0 = 0; t0 < LCH; t0 += 4) {
        float o4[4];
#pragma unroll
        for (int j = 0; j < 4; ++j) {
            float s = xr[t0 + j];
#pragma unroll
            for (int k = 0; k < 5; ++k) {
                float yk = fmaf(cb0[k], s, z1[k]);
                float u  = fmaf(cb1[k], s, z2[k]);
                z1[k] = fmaf(-ca1[k], yk, u);
                z2[k] = fmaf(-ca2[k], yk, cb2[k] * s);
                s = yk;
            }
            o4[j] = s;
        }
        *reinterpret_cast<float4*>(yp + t0) = make_float4(o4[0], o4[1], o4[2], o4[3]);
    }
}

extern "C" void kernel_launch(void* const* d_in, const int* in_sizes, int n_in,
                              void* d_out, int out_size, void* d_ws, size_t ws_size,
                              hipStream_t stream)
{
    const float* x  = (const float*)d_in[0];
    const float* cp = (const float*)d_in[1];
    float* out = (float*)d_out;
    float* sos = out + (size_t)NB * T_LEN;                 // sos tail of d_out

    float*        powers = (float*)d_ws;                   // NB*NPOW*100
    float*        agg    = powers + (size_t)NB * NPOW * 100;   // NB*SPB*10
    unsigned int* flags  = (unsigned int*)(agg + (size_t)NB * SPB * 10);  // NB*SPB

    eq_setup<<<dim3(NB), dim3(128), 0, stream>>>(cp, sos, powers, flags);
    eq_main<<<dim3(NB * SPB), dim3(256), 0, stream>>>(x, sos, powers, agg, flags, out);
}

// Round 9
// 50.634 us; speedup vs baseline: 1.3467x; 1.3467x over previous
//
#include <hip/hip_runtime.h>
#include <math.h>

// ParametricEQ: 5-section cascaded biquad over (32, 131072).
// 10-state linear recurrence z' = A z + b x (A block-lower-triangular).
// Wait-free 4-kernel pipeline (no atomics, no spin, no grid.sync):
//   K1  setup : RBJ coeffs (fp64) + P_m = A^(16*2^m), m=0..12.
//   K2a pass1 : per 16-sample chunk zero-state cascade; in-wave KS (P0..P5);
//               lane63 -> wave total (128 per batch).
//   K2b scan  : per batch, pair-combine + KS over 128 wave totals (P6..P12)
//               -> 128 wave seeds.
//   K2c pass2 : redo cascade+KS for in-wave exclusive prefix; seed * A^(16*lw)
//               via conditional matvecs -> exact chunk state; final cascade;
//               y through padded LDS -> fully coalesced global writes.

#define NB 32
#define LCH 16
#define T_LEN 131072
#define CPB 256                 // chunks per block (K2a/K2c)
#define BPB 32                  // blocks per batch
#define WPB 128                 // waves per batch
#define NPOW 13
#define PROW 12                 // padded row stride (floats) in LDS
#define PMAT (10 * PROW)

__constant__ double c_lo[15] = {-12.0,   20.0, 0.1,
                                -12.0,   20.0, 0.1,
                                -12.0,  200.0, 0.1,
                                -12.0, 2000.0, 0.1,
                                -12.0, 4000.0, 0.1};
__constant__ double c_hi[15] = { 12.0,  2000.0, 10.0,
                                 12.0,   200.0, 10.0,
                                 12.0,  2000.0, 10.0,
                                 12.0, 12000.0, 10.0,
                                 12.0, 16000.0, 10.0};

// ---------------- K1: coeffs + cascade matrix powers -----------------------
__global__ __launch_bounds__(128)
void eq_setup(const float* __restrict__ cp, float* __restrict__ sos_out,
              float* __restrict__ powers)
{
    int b = blockIdx.x;
    int t = threadIdx.x;
    __shared__ float  sc[5][5];
    __shared__ double Abuf[2][10][10];

    if (t < 5) {
        int k = t;
        double p[3];
#pragma unroll
        for (int j = 0; j < 3; ++j) {
            int i = k * 3 + j;
            double pv = (double)cp[b * 15 + i];
            p[j] = c_lo[i] + pv * (c_hi[i] - c_lo[i]);
        }
        double A     = exp(p[0] * (M_LN10 / 40.0));
        double w0    = 2.0 * M_PI * p[1] / 44100.0;
        double alpha = sin(w0) / (2.0 * p[2]);
        double cw    = cos(w0);
        double sA    = sqrt(A);
        double b0, b1, b2, a0, a1, a2;
        if (k == 0) {            // low shelf
            b0 =     A * ((A + 1) - (A - 1) * cw + 2 * sA * alpha);
            b1 = 2 * A * ((A - 1) - (A + 1) * cw);
            b2 =     A * ((A + 1) - (A - 1) * cw - 2 * sA * alpha);
            a0 =          (A + 1) + (A - 1) * cw + 2 * sA * alpha;
            a1 =    -2 * ((A - 1) + (A + 1) * cw);
            a2 =          (A + 1) + (A - 1) * cw - 2 * sA * alpha;
        } else if (k == 4) {     // high shelf
            b0 =     A * ((A + 1) + (A - 1) * cw + 2 * sA * alpha);
            b1 = -2 * A * ((A - 1) + (A + 1) * cw);
            b2 =     A * ((A + 1) + (A - 1) * cw - 2 * sA * alpha);
            a0 =          (A + 1) - (A - 1) * cw + 2 * sA * alpha;
            a1 =     2 * ((A - 1) - (A + 1) * cw);
            a2 =          (A + 1) - (A - 1) * cw - 2 * sA * alpha;
        } else {                 // peaking
            b0 = 1.0 + alpha * A;
            b1 = -2.0 * cw;
            b2 = 1.0 - alpha * A;
            a0 = 1.0 + alpha / A;
            a1 = -2.0 * cw;
            a2 = 1.0 - alpha / A;
        }
        double inv = 1.0 / a0;
        float fb0 = (float)(b0 * inv), fb1 = (float)(b1 * inv), fb2 = (float)(b2 * inv);
        float fa1 = (float)(a1 * inv), fa2 = (float)(a2 * inv);
        float* o = sos_out + (size_t)(b * 5 + k) * 6;
        o[0] = fb0; o[1] = fb1; o[2] = fb2; o[3] = 1.0f; o[4] = fa1; o[5] = fa2;
        sc[k][0] = fb0; sc[k][1] = fb1; sc[k][2] = fb2; sc[k][3] = fa1; sc[k][4] = fa2;
    }
    __syncthreads();

    // A (10x10): column i = one-sample cascade update of basis e_i with x=0.
    if (t < 10) {
        double z[10];
#pragma unroll
        for (int i = 0; i < 10; ++i) z[i] = 0.0;
        z[t] = 1.0;
        double s = 0.0;
        double zn[10];
#pragma unroll
        for (int k = 0; k < 5; ++k) {
            double b0 = sc[k][0], b1 = sc[k][1], b2 = sc[k][2];
            double a1 = sc[k][3], a2 = sc[k][4];
            double y = b0 * s + z[2 * k];
            zn[2 * k]     = b1 * s - a1 * y + z[2 * k + 1];
            zn[2 * k + 1] = b2 * s - a2 * y;
            s = y;
        }
#pragma unroll
        for (int r = 0; r < 10; ++r) Abuf[0][r][t] = zn[r];
    }
    __syncthreads();

    int r = t / 10, cc = t % 10;
    int cur = 0;
    for (int sq = 0; sq < 16; ++sq) {
        double acc = 0.0;
        if (t < 100) {
#pragma unroll
            for (int j = 0; j < 10; ++j) acc += Abuf[cur][r][j] * Abuf[cur][j][cc];
        }
        __syncthreads();
        if (t < 100) Abuf[cur ^ 1][r][cc] = acc;
        __syncthreads();
        cur ^= 1;
        if (sq >= 3 && t < 100) {
            int m = sq - 3;   // sq=3 -> A^16 = P_0 ... sq=15 -> A^65536 = P_12
            powers[((size_t)b * NPOW + m) * 100 + t] = (float)Abuf[cur][r][cc];
        }
    }
}

// ---- triangular affine: v = P*u (+v if ACC); row rr uses cols 0..(rr|1) ----
template<bool ACC>
__device__ __forceinline__ void affineT(const float* __restrict__ P,
                                        const float u[10], float v[10])
{
#pragma unroll
    for (int rr = 0; rr < 10; ++rr) {
        const float* rp = P + rr * PROW;
        float a = ACC ? v[rr] : 0.0f;
#pragma unroll
        for (int c = 0; c <= (rr | 1); ++c) a = fmaf(rp[c], u[c], a);
        v[rr] = a;
    }
}

__device__ __forceinline__ void matvecT(const float* __restrict__ P, float v[10])
{
    float u[10];
#pragma unroll
    for (int i = 0; i < 10; ++i) u[i] = v[i];
    affineT<false>(P, u, v);
}

__device__ __forceinline__ void stagePl(float* Pl, const float* __restrict__ powers,
                                        int b, int tid, int nthr)
{
    const float* src = powers + (size_t)b * NPOW * 100;
    for (int i = tid; i < NPOW * PMAT; i += nthr) {
        int c = i % PROW;
        int r = (i / PROW) % 10;
        int m = i / PMAT;
        Pl[i] = (c < 10) ? src[m * 100 + r * 10 + c] : 0.0f;
    }
}

// ---------------- K2a: pass1 — wave totals ---------------------------------
__global__ __launch_bounds__(256)
void eq_pass1(const float* __restrict__ x, const float* __restrict__ sos,
              const float* __restrict__ powers, float* __restrict__ wt)
{
    int blk = blockIdx.x;
    int b = blk >> 5, sp = blk & (BPB - 1);
    int tid = threadIdx.x;
    int w = tid >> 6, lw = tid & 63;

    __shared__ float Pl[NPOW * PMAT];
    stagePl(Pl, powers, b, tid, 256);

    const float* s5 = sos + (size_t)(b * 5) * 6;
    float cb0[5], cb1[5], cb2[5], ca1[5], ca2[5];
#pragma unroll
    for (int k = 0; k < 5; ++k) {
        cb0[k] = s5[k * 6 + 0]; cb1[k] = s5[k * 6 + 1]; cb2[k] = s5[k * 6 + 2];
        ca1[k] = s5[k * 6 + 4]; ca2[k] = s5[k * 6 + 5];
    }

    int c = sp * CPB + tid;
    const float* xp = x + (size_t)b * T_LEN + (size_t)c * LCH;
    float xr[LCH];
#pragma unroll
    for (int t0 = 0; t0 < LCH; t0 += 4) {
        float4 xv = *reinterpret_cast<const float4*>(xp + t0);
        xr[t0] = xv.x; xr[t0 + 1] = xv.y; xr[t0 + 2] = xv.z; xr[t0 + 3] = xv.w;
    }

    float z1[5] = {0, 0, 0, 0, 0}, z2[5] = {0, 0, 0, 0, 0};
#pragma unroll
    for (int j = 0; j < LCH; ++j) {
        float s = xr[j];
#pragma unroll
        for (int k = 0; k < 5; ++k) {
            float yk = fmaf(cb0[k], s, z1[k]);
            float u  = fmaf(cb1[k], s, z2[k]);
            z1[k] = fmaf(-ca1[k], yk, u);
            z2[k] = fmaf(-ca2[k], yk, cb2[k] * s);
            s = yk;
        }
    }
    float sv[10];
#pragma unroll
    for (int k = 0; k < 5; ++k) { sv[2 * k] = z1[k]; sv[2 * k + 1] = z2[k]; }

    __syncthreads();   // Pl staged

#pragma unroll
    for (int j = 0; j < 6; ++j) {
        const float* P = Pl + j * PMAT;
        float u[10];
#pragma unroll
        for (int i = 0; i < 10; ++i) u[i] = __shfl_up(sv[i], 1 << j);
        if (lw >= (1 << j)) affineT<true>(P, u, sv);
    }

    if (lw == 63) {
        int wid = sp * 4 + w;
        float* wp = wt + (size_t)(b * WPB + wid) * 10;
#pragma unroll
        for (int i = 0; i < 10; ++i) wp[i] = sv[i];
    }
}

// ---------------- K2b: per-batch scan over 128 wave totals -----------------
__global__ __launch_bounds__(64)
void eq_scan(const float* __restrict__ powers, const float* __restrict__ wt,
             float* __restrict__ seeds)
{
    int b = blockIdx.x;
    int l = threadIdx.x;

    __shared__ float Pl[NPOW * PMAT];
    stagePl(Pl, powers, b, l, 64);
    __syncthreads();

    // lane l owns wave-spans 2l, 2l+1 (1024 samples each)
    const float* wp = wt + (size_t)(b * WPB + 2 * l) * 10;
    float t0[10], t1[10];
#pragma unroll
    for (int i = 0; i < 10; ++i) { t0[i] = wp[i]; t1[i] = wp[10 + i]; }

    // pair total = t1 + P6*t0
    float tau[10];
#pragma unroll
    for (int i = 0; i < 10; ++i) tau[i] = t1[i];
    affineT<true>(Pl + 6 * PMAT, t0, tau);

    // KS over 64 pair totals; distance d=1<<j uses P_(7+j) = A^(2048*2^j)
#pragma unroll
    for (int j = 0; j < 6; ++j) {
        const float* P = Pl + (7 + j) * PMAT;
        float u[10];
#pragma unroll
        for (int i = 0; i < 10; ++i) u[i] = __shfl_up(tau[i], 1 << j);
        if (l >= (1 << j)) affineT<true>(P, u, tau);
    }

    // exclusive prefix = state entering span 2l
    float e[10];
#pragma unroll
    for (int i = 0; i < 10; ++i) e[i] = __shfl_up(tau[i], 1);
    if (l == 0) {
#pragma unroll
        for (int i = 0; i < 10; ++i) e[i] = 0.0f;
    }

    // seed(2l) = e ; seed(2l+1) = P6*e + t0
    float s1[10];
#pragma unroll
    for (int i = 0; i < 10; ++i) s1[i] = t0[i];
    affineT<true>(Pl + 6 * PMAT, e, s1);

    float* sp0 = seeds + (size_t)(b * WPB + 2 * l) * 10;
#pragma unroll
    for (int i = 0; i < 10; ++i) { sp0[i] = e[i]; sp0[10 + i] = s1[i]; }
}

// ---------------- K2c: pass2 — exact states + output -----------------------
__global__ __launch_bounds__(256)
void eq_pass2(const float* __restrict__ x, const float* __restrict__ sos,
              const float* __restrict__ powers, const float* __restrict__ seeds,
              float* __restrict__ y)
{
    int blk = blockIdx.x;
    int b = blk >> 5, sp = blk & (BPB - 1);
    int tid = threadIdx.x;
    int w = tid >> 6, lw = tid & 63;

    __shared__ float Pl[NPOW * PMAT];       // 6.24 KB
    __shared__ float ys[CPB * 17];          // 17.4 KB, stride-17 padded
    stagePl(Pl, powers, b, tid, 256);

    const float* s5 = sos + (size_t)(b * 5) * 6;
    float cb0[5], cb1[5], cb2[5], ca1[5], ca2[5];
#pragma unroll
    for (int k = 0; k < 5; ++k) {
        cb0[k] = s5[k * 6 + 0]; cb1[k] = s5[k * 6 + 1]; cb2[k] = s5[k * 6 + 2];
        ca1[k] = s5[k * 6 + 4]; ca2[k] = s5[k * 6 + 5];
    }

    int c = sp * CPB + tid;
    const float* xp = x + (size_t)b * T_LEN + (size_t)c * LCH;
    float xr[LCH];
#pragma unroll
    for (int t0 = 0; t0 < LCH; t0 += 4) {
        float4 xv = *reinterpret_cast<const float4*>(xp + t0);
        xr[t0] = xv.x; xr[t0 + 1] = xv.y; xr[t0 + 2] = xv.z; xr[t0 + 3] = xv.w;
    }

    // zero-state cascade (for in-wave prefix)
    float z1[5] = {0, 0, 0, 0, 0}, z2[5] = {0, 0, 0, 0, 0};
#pragma unroll
    for (int j = 0; j < LCH; ++j) {
        float s = xr[j];
#pragma unroll
        for (int k = 0; k < 5; ++k) {
            float yk = fmaf(cb0[k], s, z1[k]);
            float u  = fmaf(cb1[k], s, z2[k]);
            z1[k] = fmaf(-ca1[k], yk, u);
            z2[k] = fmaf(-ca2[k], yk, cb2[k] * s);
            s = yk;
        }
    }
    float sv[10];
#pragma unroll
    for (int k = 0; k < 5; ++k) { sv[2 * k] = z1[k]; sv[2 * k + 1] = z2[k]; }

    __syncthreads();   // Pl staged

#pragma unroll
    for (int j = 0; j < 6; ++j) {
        const float* P = Pl + j * PMAT;
        float u[10];
#pragma unroll
        for (int i = 0; i < 10; ++i) u[i] = __shfl_up(sv[i], 1 << j);
        if (lw >= (1 << j)) affineT<true>(P, u, sv);
    }
    float es[10];
#pragma unroll
    for (int i = 0; i < 10; ++i) es[i] = __shfl_up(sv[i], 1);
    if (lw == 0) {
#pragma unroll
        for (int i = 0; i < 10; ++i) es[i] = 0.0f;
    }

    // wave seed -> this chunk: F = A^(16*lw) * seed (powers commute), + es
    int wid = sp * 4 + w;
    const float* sdp = seeds + (size_t)(b * WPB + wid) * 10;
    float F[10];
#pragma unroll
    for (int i = 0; i < 10; ++i) F[i] = sdp[i];
#pragma unroll
    for (int m = 0; m < 6; ++m) {
        if ((lw >> m) & 1) matvecT(Pl + m * PMAT, F);
    }
#pragma unroll
    for (int k = 0; k < 5; ++k) {
        z1[k] = F[2 * k]     + es[2 * k];
        z2[k] = F[2 * k + 1] + es[2 * k + 1];
    }

    // final cascade -> LDS (padded stride 17)
    float* yl = ys + tid * 17;
#pragma unroll
    for (int j = 0; j < LCH; ++j) {
        float s = xr[j];
#pragma unroll
        for (int k = 0; k < 5; ++k) {
            float yk = fmaf(cb0[k], s, z1[k]);
            float u  = fmaf(cb1[k], s, z2[k]);
            z1[k] = fmaf(-ca1[k], yk, u);
            z2[k] = fmaf(-ca2[k], yk, cb2[k] * s);
            s = yk;
        }
        yl[j] = s;
    }
    __syncthreads();

    // coalesced copy-out: 256 threads x 4 float4 = 4096 samples
    float* yg = y + (size_t)b * T_LEN + (size_t)sp * (CPB * LCH);
#pragma unroll
    for (int it = 0; it < (CPB * LCH) / (256 * 4); ++it) {
        int i = (tid + it * 256) * 4;
        int p = (i >> 4) * 17 + (i & 15);
        *reinterpret_cast<float4*>(yg + i) =
            make_float4(ys[p], ys[p + 1], ys[p + 2], ys[p + 3]);
    }
}

extern "C" void kernel_launch(void* const* d_in, const int* in_sizes, int n_in,
                              void* d_out, int out_size, void* d_ws, size_t ws_size,
                              hipStream_t stream)
{
    const float* x  = (const float*)d_in[0];
    const float* cp = (const float*)d_in[1];
    float* out = (float*)d_out;
    float* sos = out + (size_t)NB * T_LEN;          // sos tail of d_out

    float* powers = (float*)d_ws;                   // NB*NPOW*100
    float* wt     = powers + (size_t)NB * NPOW * 100;   // NB*WPB*10
    float* seeds  = wt + (size_t)NB * WPB * 10;         // NB*WPB*10

    eq_setup<<<dim3(NB), dim3(128), 0, stream>>>(cp, sos, powers);
    eq_pass1<<<dim3(NB * BPB), dim3(256), 0, stream>>>(x, sos, powers, wt);
    eq_scan <<<dim3(NB), dim3(64), 0, stream>>>(powers, wt, seeds);
    eq_pass2<<<dim3(NB * BPB), dim3(256), 0, stream>>>(x, sos, powers, seeds, out);
}

// Round 10
// 45.420 us; speedup vs baseline: 1.5013x; 1.1148x over previous
//
#include <hip/hip_runtime.h>
#include <math.h>

// ParametricEQ: 5-section cascaded biquad over (32, 131072).
// 10-state linear recurrence z' = A z + b x (A block-lower-triangular).
// Wait-free 4-kernel pipeline; P matrices are read via wave-uniform global
// loads (-> s_load / SGPR operands), never through LDS or per-lane VMEM.
//   K1  setup : RBJ coeffs (fp64) + P_m = A^(16*2^m), m=0..12.
//   K2a pass1 : per 16-sample chunk zero-state cascade; in-wave KS (P0..P5);
//               store per-chunk exclusive prefix es (i-major, coalesced);
//               lane63 -> wave total (128 per batch).
//   K2b scan  : per batch, pair-combine + KS over 128 wave totals (P6..P12)
//               -> 128 wave seeds.
//   K2c pass2 : F = A^(16*lw)*seed (conditional matvecs) + es -> exact state;
//               final cascade; y through padded LDS -> coalesced writes.

#define NB 32
#define LCH 16
#define T_LEN 131072
#define CPB 256                 // chunks per block (K2a/K2c)
#define BPB 32                  // blocks per batch
#define CCH 8192                // chunks per batch
#define WPB 128                 // waves per batch
#define NPOW 13

__constant__ double c_lo[15] = {-12.0,   20.0, 0.1,
                                -12.0,   20.0, 0.1,
                                -12.0,  200.0, 0.1,
                                -12.0, 2000.0, 0.1,
                                -12.0, 4000.0, 0.1};
__constant__ double c_hi[15] = { 12.0,  2000.0, 10.0,
                                 12.0,   200.0, 10.0,
                                 12.0,  2000.0, 10.0,
                                 12.0, 12000.0, 10.0,
                                 12.0, 16000.0, 10.0};

// ---------------- K1: coeffs + cascade matrix powers -----------------------
__global__ __launch_bounds__(128)
void eq_setup(const float* __restrict__ cp, float* __restrict__ sos_out,
              float* __restrict__ powers)
{
    int b = blockIdx.x;
    int t = threadIdx.x;
    __shared__ float  sc[5][5];
    __shared__ double Abuf[2][10][10];

    if (t < 5) {
        int k = t;
        double p[3];
#pragma unroll
        for (int j = 0; j < 3; ++j) {
            int i = k * 3 + j;
            double pv = (double)cp[b * 15 + i];
            p[j] = c_lo[i] + pv * (c_hi[i] - c_lo[i]);
        }
        double A     = exp(p[0] * (M_LN10 / 40.0));
        double w0    = 2.0 * M_PI * p[1] / 44100.0;
        double alpha = sin(w0) / (2.0 * p[2]);
        double cw    = cos(w0);
        double sA    = sqrt(A);
        double b0, b1, b2, a0, a1, a2;
        if (k == 0) {            // low shelf
            b0 =     A * ((A + 1) - (A - 1) * cw + 2 * sA * alpha);
            b1 = 2 * A * ((A - 1) - (A + 1) * cw);
            b2 =     A * ((A + 1) - (A - 1) * cw - 2 * sA * alpha);
            a0 =          (A + 1) + (A - 1) * cw + 2 * sA * alpha;
            a1 =    -2 * ((A - 1) + (A + 1) * cw);
            a2 =          (A + 1) + (A - 1) * cw - 2 * sA * alpha;
        } else if (k == 4) {     // high shelf
            b0 =     A * ((A + 1) + (A - 1) * cw + 2 * sA * alpha);
            b1 = -2 * A * ((A - 1) + (A + 1) * cw);
            b2 =     A * ((A + 1) + (A - 1) * cw - 2 * sA * alpha);
            a0 =          (A + 1) - (A - 1) * cw + 2 * sA * alpha;
            a1 =     2 * ((A - 1) - (A + 1) * cw);
            a2 =          (A + 1) - (A - 1) * cw - 2 * sA * alpha;
        } else {                 // peaking
            b0 = 1.0 + alpha * A;
            b1 = -2.0 * cw;
            b2 = 1.0 - alpha * A;
            a0 = 1.0 + alpha / A;
            a1 = -2.0 * cw;
            a2 = 1.0 - alpha / A;
        }
        double inv = 1.0 / a0;
        float fb0 = (float)(b0 * inv), fb1 = (float)(b1 * inv), fb2 = (float)(b2 * inv);
        float fa1 = (float)(a1 * inv), fa2 = (float)(a2 * inv);
        float* o = sos_out + (size_t)(b * 5 + k) * 6;
        o[0] = fb0; o[1] = fb1; o[2] = fb2; o[3] = 1.0f; o[4] = fa1; o[5] = fa2;
        sc[k][0] = fb0; sc[k][1] = fb1; sc[k][2] = fb2; sc[k][3] = fa1; sc[k][4] = fa2;
    }
    __syncthreads();

    // A (10x10): column i = one-sample cascade update of basis e_i with x=0.
    if (t < 10) {
        double z[10];
#pragma unroll
        for (int i = 0; i < 10; ++i) z[i] = 0.0;
        z[t] = 1.0;
        double s = 0.0;
        double zn[10];
#pragma unroll
        for (int k = 0; k < 5; ++k) {
            double b0 = sc[k][0], b1 = sc[k][1], b2 = sc[k][2];
            double a1 = sc[k][3], a2 = sc[k][4];
            double y = b0 * s + z[2 * k];
            zn[2 * k]     = b1 * s - a1 * y + z[2 * k + 1];
            zn[2 * k + 1] = b2 * s - a2 * y;
            s = y;
        }
#pragma unroll
        for (int r = 0; r < 10; ++r) Abuf[0][r][t] = zn[r];
    }
    __syncthreads();

    int r = t / 10, cc = t % 10;
    int cur = 0;
    for (int sq = 0; sq < 16; ++sq) {
        double acc = 0.0;
        if (t < 100) {
#pragma unroll
            for (int j = 0; j < 10; ++j) acc += Abuf[cur][r][j] * Abuf[cur][j][cc];
        }
        __syncthreads();
        if (t < 100) Abuf[cur ^ 1][r][cc] = acc;
        __syncthreads();
        cur ^= 1;
        if (sq >= 3 && t < 100) {
            int m = sq - 3;   // sq=3 -> A^16 = P_0 ... sq=15 -> A^65536 = P_12
            powers[((size_t)b * NPOW + m) * 100 + t] = (float)Abuf[cur][r][cc];
        }
    }
}

// ---- triangular affine: v = P*u (+v if ACC); P is a GLOBAL 10x10 matrix
// addressed wave-uniformly -> compiler emits s_load, FMAs take SGPR operands.
// Row rr uses cols 0..(rr|1) (block-lower-triangular, exact zeros). ----
template<bool ACC>
__device__ __forceinline__ void affineT(const float* __restrict__ P,
                                        const float u[10], float v[10])
{
#pragma unroll
    for (int rr = 0; rr < 10; ++rr) {
        const float* rp = P + rr * 10;
        float a = ACC ? v[rr] : 0.0f;
#pragma unroll
        for (int c = 0; c <= (rr | 1); ++c) a = fmaf(rp[c], u[c], a);
        v[rr] = a;
    }
}

__device__ __forceinline__ void matvecT(const float* __restrict__ P, float v[10])
{
    float u[10];
#pragma unroll
    for (int i = 0; i < 10; ++i) u[i] = v[i];
    affineT<false>(P, u, v);
}

// ---------------- K2a: pass1 — per-chunk exclusive prefixes + wave totals ---
__global__ __launch_bounds__(256, 4)
void eq_pass1(const float* __restrict__ x, const float* __restrict__ sos,
              const float* __restrict__ powers, float* __restrict__ es_g,
              float* __restrict__ wt)
{
    int blk = blockIdx.x;
    int b = blk >> 5, sp = blk & (BPB - 1);
    int tid = threadIdx.x;
    int w = tid >> 6, lw = tid & 63;

    const float* s5 = sos + (size_t)(b * 5) * 6;
    float cb0[5], cb1[5], cb2[5], ca1[5], ca2[5];
#pragma unroll
    for (int k = 0; k < 5; ++k) {
        cb0[k] = s5[k * 6 + 0]; cb1[k] = s5[k * 6 + 1]; cb2[k] = s5[k * 6 + 2];
        ca1[k] = s5[k * 6 + 4]; ca2[k] = s5[k * 6 + 5];
    }

    int c = sp * CPB + tid;
    const float* xp = x + (size_t)b * T_LEN + (size_t)c * LCH;
    float xr[LCH];
#pragma unroll
    for (int t0 = 0; t0 < LCH; t0 += 4) {
        float4 xv = *reinterpret_cast<const float4*>(xp + t0);
        xr[t0] = xv.x; xr[t0 + 1] = xv.y; xr[t0 + 2] = xv.z; xr[t0 + 3] = xv.w;
    }

    // zero-state cascade -> chunk end state
    float z1[5] = {0, 0, 0, 0, 0}, z2[5] = {0, 0, 0, 0, 0};
#pragma unroll
    for (int j = 0; j < LCH; ++j) {
        float s = xr[j];
#pragma unroll
        for (int k = 0; k < 5; ++k) {
            float yk = fmaf(cb0[k], s, z1[k]);
            float u  = fmaf(cb1[k], s, z2[k]);
            z1[k] = fmaf(-ca1[k], yk, u);
            z2[k] = fmaf(-ca2[k], yk, cb2[k] * s);
            s = yk;
        }
    }
    float sv[10];
#pragma unroll
    for (int k = 0; k < 5; ++k) { sv[2 * k] = z1[k]; sv[2 * k + 1] = z2[k]; }

    // in-wave KS scan over 64 chunks (P_0..P_5, SGPR operands)
    const float* Pb = powers + (size_t)b * NPOW * 100;
#pragma unroll
    for (int j = 0; j < 6; ++j) {
        const float* P = Pb + j * 100;
        float u[10];
#pragma unroll
        for (int i = 0; i < 10; ++i) u[i] = __shfl_up(sv[i], 1 << j);
        if (lw >= (1 << j)) affineT<true>(P, u, sv);
    }

    // exclusive in-wave prefix -> global (i-major, coalesced)
    float es[10];
#pragma unroll
    for (int i = 0; i < 10; ++i) es[i] = __shfl_up(sv[i], 1);
    if (lw == 0) {
#pragma unroll
        for (int i = 0; i < 10; ++i) es[i] = 0.0f;
    }
    float* ep = es_g + (size_t)b * 10 * CCH + c;
#pragma unroll
    for (int i = 0; i < 10; ++i) ep[(size_t)i * CCH] = es[i];

    if (lw == 63) {
        int wid = sp * 4 + w;
        float* wp = wt + (size_t)(b * WPB + wid) * 10;
#pragma unroll
        for (int i = 0; i < 10; ++i) wp[i] = sv[i];
    }
}

// ---------------- K2b: per-batch scan over 128 wave totals -----------------
__global__ __launch_bounds__(64)
void eq_scan(const float* __restrict__ powers, const float* __restrict__ wt,
             float* __restrict__ seeds)
{
    int b = blockIdx.x;
    int l = threadIdx.x;
    const float* Pb = powers + (size_t)b * NPOW * 100;

    // lane l owns wave-spans 2l, 2l+1 (1024 samples each)
    const float* wp = wt + (size_t)(b * WPB + 2 * l) * 10;
    float t0[10], t1[10];
#pragma unroll
    for (int i = 0; i < 10; ++i) { t0[i] = wp[i]; t1[i] = wp[10 + i]; }

    // pair total = t1 + P6*t0
    float tau[10];
#pragma unroll
    for (int i = 0; i < 10; ++i) tau[i] = t1[i];
    affineT<true>(Pb + 6 * 100, t0, tau);

    // KS over 64 pair totals; distance 1<<j uses P_(7+j) = A^(2048*2^j)
#pragma unroll
    for (int j = 0; j < 6; ++j) {
        const float* P = Pb + (7 + j) * 100;
        float u[10];
#pragma unroll
        for (int i = 0; i < 10; ++i) u[i] = __shfl_up(tau[i], 1 << j);
        if (l >= (1 << j)) affineT<true>(P, u, tau);
    }

    // exclusive prefix = state entering span 2l
    float e[10];
#pragma unroll
    for (int i = 0; i < 10; ++i) e[i] = __shfl_up(tau[i], 1);
    if (l == 0) {
#pragma unroll
        for (int i = 0; i < 10; ++i) e[i] = 0.0f;
    }

    // seed(2l) = e ; seed(2l+1) = P6*e + t0
    float s1[10];
#pragma unroll
    for (int i = 0; i < 10; ++i) s1[i] = t0[i];
    affineT<true>(Pb + 6 * 100, e, s1);

    float* sp0 = seeds + (size_t)(b * WPB + 2 * l) * 10;
#pragma unroll
    for (int i = 0; i < 10; ++i) { sp0[i] = e[i]; sp0[10 + i] = s1[i]; }
}

// ---------------- K2c: pass2 — exact states + output -----------------------
__global__ __launch_bounds__(256, 4)
void eq_pass2(const float* __restrict__ x, const float* __restrict__ sos,
              const float* __restrict__ powers, const float* __restrict__ seeds,
              const float* __restrict__ es_g, float* __restrict__ y)
{
    int blk = blockIdx.x;
    int b = blk >> 5, sp = blk & (BPB - 1);
    int tid = threadIdx.x;
    int w = tid >> 6, lw = tid & 63;

    __shared__ float ys[CPB * 17];          // 17.4 KB, stride-17 padded

    const float* s5 = sos + (size_t)(b * 5) * 6;
    float cb0[5], cb1[5], cb2[5], ca1[5], ca2[5];
#pragma unroll
    for (int k = 0; k < 5; ++k) {
        cb0[k] = s5[k * 6 + 0]; cb1[k] = s5[k * 6 + 1]; cb2[k] = s5[k * 6 + 2];
        ca1[k] = s5[k * 6 + 4]; ca2[k] = s5[k * 6 + 5];
    }

    int c = sp * CPB + tid;
    const float* xp = x + (size_t)b * T_LEN + (size_t)c * LCH;
    float xr[LCH];
#pragma unroll
    for (int t0 = 0; t0 < LCH; t0 += 4) {
        float4 xv = *reinterpret_cast<const float4*>(xp + t0);
        xr[t0] = xv.x; xr[t0 + 1] = xv.y; xr[t0 + 2] = xv.z; xr[t0 + 3] = xv.w;
    }

    // wave seed -> this chunk: F = A^(16*lw) * seed (powers commute), + es
    const float* Pb = powers + (size_t)b * NPOW * 100;
    int wid = sp * 4 + w;
    const float* sdp = seeds + (size_t)(b * WPB + wid) * 10;
    float F[10];
#pragma unroll
    for (int i = 0; i < 10; ++i) F[i] = sdp[i];
#pragma unroll
    for (int m = 0; m < 6; ++m) {
        if ((lw >> m) & 1) matvecT(Pb + m * 100, F);
    }

    const float* ep = es_g + (size_t)b * 10 * CCH + c;
    float z1[5], z2[5];
#pragma unroll
    for (int k = 0; k < 5; ++k) {
        z1[k] = F[2 * k]     + ep[(size_t)(2 * k) * CCH];
        z2[k] = F[2 * k + 1] + ep[(size_t)(2 * k + 1) * CCH];
    }

    // final cascade -> LDS (padded stride 17)
    float* yl = ys + tid * 17;
#pragma unroll
    for (int j = 0; j < LCH; ++j) {
        float s = xr[j];
#pragma unroll
        for (int k = 0; k < 5; ++k) {
            float yk = fmaf(cb0[k], s, z1[k]);
            float u  = fmaf(cb1[k], s, z2[k]);
            z1[k] = fmaf(-ca1[k], yk, u);
            z2[k] = fmaf(-ca2[k], yk, cb2[k] * s);
            s = yk;
        }
        yl[j] = s;
    }
    __syncthreads();

    // coalesced copy-out: 256 threads x 4 float4 = 4096 samples
    float* yg = y + (size_t)b * T_LEN + (size_t)sp * (CPB * LCH);
#pragma unroll
    for (int it = 0; it < (CPB * LCH) / (256 * 4); ++it) {
        int i = (tid + it * 256) * 4;
        int p = (i >> 4) * 17 + (i & 15);
        *reinterpret_cast<float4*>(yg + i) =
            make_float4(ys[p], ys[p + 1], ys[p + 2], ys[p + 3]);
    }
}

extern "C" void kernel_launch(void* const* d_in, const int* in_sizes, int n_in,
                              void* d_out, int out_size, void* d_ws, size_t ws_size,
                              hipStream_t stream)
{
    const float* x  = (const float*)d_in[0];
    const float* cp = (const float*)d_in[1];
    float* out = (float*)d_out;
    float* sos = out + (size_t)NB * T_LEN;          // sos tail of d_out

    float* powers = (float*)d_ws;                        // NB*NPOW*100
    float* wt     = powers + (size_t)NB * NPOW * 100;    // NB*WPB*10
    float* seeds  = wt + (size_t)NB * WPB * 10;          // NB*WPB*10
    float* es_g   = seeds + (size_t)NB * WPB * 10;       // NB*10*CCH

    eq_setup<<<dim3(NB), dim3(128), 0, stream>>>(cp, sos, powers);
    eq_pass1<<<dim3(NB * BPB), dim3(256), 0, stream>>>(x, sos, powers, es_g, wt);
    eq_scan <<<dim3(NB), dim3(64), 0, stream>>>(powers, wt, seeds);
    eq_pass2<<<dim3(NB * BPB), dim3(256), 0, stream>>>(x, sos, powers, seeds, es_g, out);
}

// Round 11
// 44.507 us; speedup vs baseline: 1.5321x; 1.0205x over previous
//
#include <hip/hip_runtime.h>
#include <math.h>

// ParametricEQ: 5-section cascaded biquad over (32, 131072).
// 10-state linear recurrence z' = A z + b x (A block-lower-triangular).
// Wait-free 3-kernel pipeline; P matrices are read via wave-uniform global
// loads (-> s_load / SGPR operands), never through LDS or per-lane VMEM.
//   K1  setup : RBJ coeffs (fp64) + P_m = A^(16*2^m), m=0..12.
//   K2a pass1 : per 16-sample chunk zero-state cascade; in-wave KS (P0..P5);
//               store per-chunk exclusive prefix es (i-major, coalesced);
//               lane63 -> wave total (128 per batch).
//   K2b pass2 : per-block redundant scan over this batch's 128 wave totals
//               (pair-combine P6 + KS P7..P12) -> own wave seed via shfl;
//               F = A^(16*lw)*seed + es -> exact state; final cascade;
//               y through padded LDS -> coalesced writes.

#define NB 32
#define LCH 16
#define T_LEN 131072
#define CPB 256                 // chunks per block (K2a/K2b)
#define BPB 32                  // blocks per batch
#define CCH 8192                // chunks per batch
#define WPB 128                 // waves per batch
#define NPOW 13

__constant__ double c_lo[15] = {-12.0,   20.0, 0.1,
                                -12.0,   20.0, 0.1,
                                -12.0,  200.0, 0.1,
                                -12.0, 2000.0, 0.1,
                                -12.0, 4000.0, 0.1};
__constant__ double c_hi[15] = { 12.0,  2000.0, 10.0,
                                 12.0,   200.0, 10.0,
                                 12.0,  2000.0, 10.0,
                                 12.0, 12000.0, 10.0,
                                 12.0, 16000.0, 10.0};

// ---------------- K1: coeffs + cascade matrix powers -----------------------
__global__ __launch_bounds__(128)
void eq_setup(const float* __restrict__ cp, float* __restrict__ sos_out,
              float* __restrict__ powers)
{
    int b = blockIdx.x;
    int t = threadIdx.x;
    __shared__ float  sc[5][5];
    __shared__ double Abuf[2][10][10];

    if (t < 5) {
        int k = t;
        double p[3];
#pragma unroll
        for (int j = 0; j < 3; ++j) {
            int i = k * 3 + j;
            double pv = (double)cp[b * 15 + i];
            p[j] = c_lo[i] + pv * (c_hi[i] - c_lo[i]);
        }
        double A     = exp(p[0] * (M_LN10 / 40.0));
        double w0    = 2.0 * M_PI * p[1] / 44100.0;
        double alpha = sin(w0) / (2.0 * p[2]);
        double cw    = cos(w0);
        double sA    = sqrt(A);
        double b0, b1, b2, a0, a1, a2;
        if (k == 0) {            // low shelf
            b0 =     A * ((A + 1) - (A - 1) * cw + 2 * sA * alpha);
            b1 = 2 * A * ((A - 1) - (A + 1) * cw);
            b2 =     A * ((A + 1) - (A - 1) * cw - 2 * sA * alpha);
            a0 =          (A + 1) + (A - 1) * cw + 2 * sA * alpha;
            a1 =    -2 * ((A - 1) + (A + 1) * cw);
            a2 =          (A + 1) + (A - 1) * cw - 2 * sA * alpha;
        } else if (k == 4) {     // high shelf
            b0 =     A * ((A + 1) + (A - 1) * cw + 2 * sA * alpha);
            b1 = -2 * A * ((A - 1) + (A + 1) * cw);
            b2 =     A * ((A + 1) + (A - 1) * cw - 2 * sA * alpha);
            a0 =          (A + 1) - (A - 1) * cw + 2 * sA * alpha;
            a1 =     2 * ((A - 1) - (A + 1) * cw);
            a2 =          (A + 1) - (A - 1) * cw - 2 * sA * alpha;
        } else {                 // peaking
            b0 = 1.0 + alpha * A;
            b1 = -2.0 * cw;
            b2 = 1.0 - alpha * A;
            a0 = 1.0 + alpha / A;
            a1 = -2.0 * cw;
            a2 = 1.0 - alpha / A;
        }
        double inv = 1.0 / a0;
        float fb0 = (float)(b0 * inv), fb1 = (float)(b1 * inv), fb2 = (float)(b2 * inv);
        float fa1 = (float)(a1 * inv), fa2 = (float)(a2 * inv);
        float* o = sos_out + (size_t)(b * 5 + k) * 6;
        o[0] = fb0; o[1] = fb1; o[2] = fb2; o[3] = 1.0f; o[4] = fa1; o[5] = fa2;
        sc[k][0] = fb0; sc[k][1] = fb1; sc[k][2] = fb2; sc[k][3] = fa1; sc[k][4] = fa2;
    }
    __syncthreads();

    // A (10x10): column i = one-sample cascade update of basis e_i with x=0.
    if (t < 10) {
        double z[10];
#pragma unroll
        for (int i = 0; i < 10; ++i) z[i] = 0.0;
        z[t] = 1.0;
        double s = 0.0;
        double zn[10];
#pragma unroll
        for (int k = 0; k < 5; ++k) {
            double b0 = sc[k][0], b1 = sc[k][1], b2 = sc[k][2];
            double a1 = sc[k][3], a2 = sc[k][4];
            double y = b0 * s + z[2 * k];
            zn[2 * k]     = b1 * s - a1 * y + z[2 * k + 1];
            zn[2 * k + 1] = b2 * s - a2 * y;
            s = y;
        }
#pragma unroll
        for (int r = 0; r < 10; ++r) Abuf[0][r][t] = zn[r];
    }
    __syncthreads();

    int r = t / 10, cc = t % 10;
    int cur = 0;
    for (int sq = 0; sq < 16; ++sq) {
        double acc = 0.0;
        if (t < 100) {
#pragma unroll
            for (int j = 0; j < 10; ++j) acc += Abuf[cur][r][j] * Abuf[cur][j][cc];
        }
        __syncthreads();
        if (t < 100) Abuf[cur ^ 1][r][cc] = acc;
        __syncthreads();
        cur ^= 1;
        if (sq >= 3 && t < 100) {
            int m = sq - 3;   // sq=3 -> A^16 = P_0 ... sq=15 -> A^65536 = P_12
            powers[((size_t)b * NPOW + m) * 100 + t] = (float)Abuf[cur][r][cc];
        }
    }
}

// ---- triangular affine: v = P*u (+v if ACC); P is a GLOBAL 10x10 matrix
// addressed wave-uniformly -> compiler emits s_load, FMAs take SGPR operands.
// Row rr uses cols 0..(rr|1) (block-lower-triangular, exact zeros). ----
template<bool ACC>
__device__ __forceinline__ void affineT(const float* __restrict__ P,
                                        const float u[10], float v[10])
{
#pragma unroll
    for (int rr = 0; rr < 10; ++rr) {
        const float* rp = P + rr * 10;
        float a = ACC ? v[rr] : 0.0f;
#pragma unroll
        for (int c = 0; c <= (rr | 1); ++c) a = fmaf(rp[c], u[c], a);
        v[rr] = a;
    }
}

__device__ __forceinline__ void matvecT(const float* __restrict__ P, float v[10])
{
    float u[10];
#pragma unroll
    for (int i = 0; i < 10; ++i) u[i] = v[i];
    affineT<false>(P, u, v);
}

// ---------------- K2a: pass1 — per-chunk exclusive prefixes + wave totals ---
__global__ __launch_bounds__(256, 4)
void eq_pass1(const float* __restrict__ x, const float* __restrict__ sos,
              const float* __restrict__ powers, float* __restrict__ es_g,
              float* __restrict__ wt)
{
    int blk = blockIdx.x;
    int b = blk >> 5, sp = blk & (BPB - 1);
    int tid = threadIdx.x;
    int w = tid >> 6, lw = tid & 63;

    const float* s5 = sos + (size_t)(b * 5) * 6;
    float cb0[5], cb1[5], cb2[5], ca1[5], ca2[5];
#pragma unroll
    for (int k = 0; k < 5; ++k) {
        cb0[k] = s5[k * 6 + 0]; cb1[k] = s5[k * 6 + 1]; cb2[k] = s5[k * 6 + 2];
        ca1[k] = s5[k * 6 + 4]; ca2[k] = s5[k * 6 + 5];
    }

    int c = sp * CPB + tid;
    const float* xp = x + (size_t)b * T_LEN + (size_t)c * LCH;
    float xr[LCH];
#pragma unroll
    for (int t0 = 0; t0 < LCH; t0 += 4) {
        float4 xv = *reinterpret_cast<const float4*>(xp + t0);
        xr[t0] = xv.x; xr[t0 + 1] = xv.y; xr[t0 + 2] = xv.z; xr[t0 + 3] = xv.w;
    }

    // zero-state cascade -> chunk end state
    float z1[5] = {0, 0, 0, 0, 0}, z2[5] = {0, 0, 0, 0, 0};
#pragma unroll
    for (int j = 0; j < LCH; ++j) {
        float s = xr[j];
#pragma unroll
        for (int k = 0; k < 5; ++k) {
            float yk = fmaf(cb0[k], s, z1[k]);
            float u  = fmaf(cb1[k], s, z2[k]);
            z1[k] = fmaf(-ca1[k], yk, u);
            z2[k] = fmaf(-ca2[k], yk, cb2[k] * s);
            s = yk;
        }
    }
    float sv[10];
#pragma unroll
    for (int k = 0; k < 5; ++k) { sv[2 * k] = z1[k]; sv[2 * k + 1] = z2[k]; }

    // in-wave KS scan over 64 chunks (P_0..P_5, SGPR operands)
    const float* Pb = powers + (size_t)b * NPOW * 100;
#pragma unroll
    for (int j = 0; j < 6; ++j) {
        const float* P = Pb + j * 100;
        float u[10];
#pragma unroll
        for (int i = 0; i < 10; ++i) u[i] = __shfl_up(sv[i], 1 << j);
        if (lw >= (1 << j)) affineT<true>(P, u, sv);
    }

    // exclusive in-wave prefix -> global (i-major, coalesced)
    float es[10];
#pragma unroll
    for (int i = 0; i < 10; ++i) es[i] = __shfl_up(sv[i], 1);
    if (lw == 0) {
#pragma unroll
        for (int i = 0; i < 10; ++i) es[i] = 0.0f;
    }
    float* ep = es_g + (size_t)b * 10 * CCH + c;
#pragma unroll
    for (int i = 0; i < 10; ++i) ep[(size_t)i * CCH] = es[i];

    if (lw == 63) {
        int wid = sp * 4 + w;
        float* wp = wt + (size_t)(b * WPB + wid) * 10;
#pragma unroll
        for (int i = 0; i < 10; ++i) wp[i] = sv[i];
    }
}

// ---------------- K2b: pass2 — fused scan + exact states + output ----------
__global__ __launch_bounds__(256, 4)
void eq_pass2(const float* __restrict__ x, const float* __restrict__ sos,
              const float* __restrict__ powers, const float* __restrict__ wt,
              const float* __restrict__ es_g, float* __restrict__ y)
{
    int blk = blockIdx.x;
    int b = blk >> 5, sp = blk & (BPB - 1);
    int tid = threadIdx.x;
    int w = tid >> 6, lw = tid & 63;

    __shared__ float ys[CPB * 17];          // 17.4 KB, stride-17 padded

    const float* Pb = powers + (size_t)b * NPOW * 100;
    int wid = sp * 4 + w;                   // this wave's global wave index

    // ---- in-wave redundant scan over this batch's 128 wave totals ----
    // lane l owns wave-spans 2l, 2l+1 (each a 1024-sample zero-state total)
    const float* wp = wt + (size_t)(b * WPB + 2 * lw) * 10;
    float t0[10], t1[10];
#pragma unroll
    for (int i = 0; i < 10; ++i) { t0[i] = wp[i]; t1[i] = wp[10 + i]; }

    float tau[10];
#pragma unroll
    for (int i = 0; i < 10; ++i) tau[i] = t1[i];
    affineT<true>(Pb + 6 * 100, t0, tau);   // pair total (2048 samples)

#pragma unroll
    for (int j = 0; j < 6; ++j) {           // KS over 64 pairs, P_(7+j)
        const float* P = Pb + (7 + j) * 100;
        float u[10];
#pragma unroll
        for (int i = 0; i < 10; ++i) u[i] = __shfl_up(tau[i], 1 << j);
        if (lw >= (1 << j)) affineT<true>(P, u, tau);
    }

    float e[10];                            // entering state of pair lw (wave 2lw)
#pragma unroll
    for (int i = 0; i < 10; ++i) e[i] = __shfl_up(tau[i], 1);
    if (lw == 0) {
#pragma unroll
        for (int i = 0; i < 10; ++i) e[i] = 0.0f;
    }
    float s1[10];                           // entering state of wave 2lw+1
#pragma unroll
    for (int i = 0; i < 10; ++i) s1[i] = t0[i];
    affineT<true>(Pb + 6 * 100, e, s1);

    // this wave's seed: lane (wid>>1)'s e (wid even) or s1 (wid odd)
    float F[10];
#pragma unroll
    for (int i = 0; i < 10; ++i)
        F[i] = __shfl((wid & 1) ? s1[i] : e[i], wid >> 1);

    // ---- x load ----
    int c = sp * CPB + tid;
    const float* xp = x + (size_t)b * T_LEN + (size_t)c * LCH;
    float xr[LCH];
#pragma unroll
    for (int t2 = 0; t2 < LCH; t2 += 4) {
        float4 xv = *reinterpret_cast<const float4*>(xp + t2);
        xr[t2] = xv.x; xr[t2 + 1] = xv.y; xr[t2 + 2] = xv.z; xr[t2 + 3] = xv.w;
    }

    // ---- F = A^(16*lw) * seed (powers commute), + es -> exact state ----
#pragma unroll
    for (int m = 0; m < 6; ++m) {
        if ((lw >> m) & 1) matvecT(Pb + m * 100, F);
    }

    const float* s5 = sos + (size_t)(b * 5) * 6;
    float cb0[5], cb1[5], cb2[5], ca1[5], ca2[5];
#pragma unroll
    for (int k = 0; k < 5; ++k) {
        cb0[k] = s5[k * 6 + 0]; cb1[k] = s5[k * 6 + 1]; cb2[k] = s5[k * 6 + 2];
        ca1[k] = s5[k * 6 + 4]; ca2[k] = s5[k * 6 + 5];
    }

    const float* ep = es_g + (size_t)b * 10 * CCH + c;
    float z1[5], z2[5];
#pragma unroll
    for (int k = 0; k < 5; ++k) {
        z1[k] = F[2 * k]     + ep[(size_t)(2 * k) * CCH];
        z2[k] = F[2 * k + 1] + ep[(size_t)(2 * k + 1) * CCH];
    }

    // ---- final cascade -> LDS (padded stride 17) ----
    float* yl = ys + tid * 17;
#pragma unroll
    for (int j = 0; j < LCH; ++j) {
        float s = xr[j];
#pragma unroll
        for (int k = 0; k < 5; ++k) {
            float yk = fmaf(cb0[k], s, z1[k]);
            float u  = fmaf(cb1[k], s, z2[k]);
            z1[k] = fmaf(-ca1[k], yk, u);
            z2[k] = fmaf(-ca2[k], yk, cb2[k] * s);
            s = yk;
        }
        yl[j] = s;
    }
    __syncthreads();

    // ---- coalesced copy-out: 256 threads x 4 float4 = 4096 samples ----
    float* yg = y + (size_t)b * T_LEN + (size_t)sp * (CPB * LCH);
#pragma unroll
    for (int it = 0; it < (CPB * LCH) / (256 * 4); ++it) {
        int i = (tid + it * 256) * 4;
        int p = (i >> 4) * 17 + (i & 15);
        *reinterpret_cast<float4*>(yg + i) =
            make_float4(ys[p], ys[p + 1], ys[p + 2], ys[p + 3]);
    }
}

extern "C" void kernel_launch(void* const* d_in, const int* in_sizes, int n_in,
                              void* d_out, int out_size, void* d_ws, size_t ws_size,
                              hipStream_t stream)
{
    const float* x  = (const float*)d_in[0];
    const float* cp = (const float*)d_in[1];
    float* out = (float*)d_out;
    float* sos = out + (size_t)NB * T_LEN;          // sos tail of d_out

    float* powers = (float*)d_ws;                        // NB*NPOW*100
    float* wt     = powers + (size_t)NB * NPOW * 100;    // NB*WPB*10
    float* es_g   = wt + (size_t)NB * WPB * 10;          // NB*10*CCH

    eq_setup<<<dim3(NB), dim3(128), 0, stream>>>(cp, sos, powers);
    eq_pass1<<<dim3(NB * BPB), dim3(256), 0, stream>>>(x, sos, powers, es_g, wt);
    eq_pass2<<<dim3(NB * BPB), dim3(256), 0, stream>>>(x, sos, powers, wt, es_g, out);
}